// Round 1
// baseline (1396.660 us; speedup 1.0000x reference)
//
#include <hip/hip_runtime.h>
#include <stdint.h>

#define D_IN   768
#define D_DICT 16384
#define NROWS  8192
#define TOPK   32
#define CAND_TARGET 40   // screening candidate count (20-sigma margin vs bf16 noise)
#define CAND_MAX    80   // strict hits in [0,40), ties packed from slot 79 down

typedef __attribute__((ext_vector_type(4))) float  f32x4;
typedef __attribute__((ext_vector_type(8))) short  s16x8;
typedef __attribute__((ext_vector_type(4))) unsigned short u16x4;

static __device__ __forceinline__ unsigned short f2bf(float f) {
    unsigned int u = __float_as_uint(f);
    unsigned int r = (u + 0x7FFFu + ((u >> 16) & 1u)) >> 16;   // RNE
    return (unsigned short)r;
}

static __device__ __forceinline__ void gload_lds16(const void* g, void* l) {
    __builtin_amdgcn_global_load_lds(
        (const __attribute__((address_space(1))) unsigned int*)g,
        (__attribute__((address_space(3))) unsigned int*)l, 16, 0, 0);
}

// ---------------- prep: fp32 -> bf16 cast (vectorized) ----------------
__global__ __launch_bounds__(256) void cast_bf16(const float4* __restrict__ in,
                                                 u16x4* __restrict__ out, int n4) {
    int idx = blockIdx.x * 256 + threadIdx.x;
    if (idx >= n4) return;
    float4 v = in[idx];
    u16x4 o;
    o.x = f2bf(v.x); o.y = f2bf(v.y); o.z = f2bf(v.z); o.w = f2bf(v.w);
    out[idx] = o;
}

// ---------------- prep: transpose W_dec [768][16384] -> [16384][768] ----------------
__global__ void transpose_wdec(const float* __restrict__ in, float* __restrict__ out) {
    __shared__ float t[32][33];
    int bx = blockIdx.x;          // along 16384 (512 tiles)
    int by = blockIdx.y;          // along 768   (24 tiles)
    int tx = threadIdx.x;         // 32
    int ty = threadIdx.y;         // 8
#pragma unroll
    for (int i = 0; i < 4; ++i)
        t[ty + i * 8][tx] = in[(size_t)(by * 32 + ty + i * 8) * D_DICT + bx * 32 + tx];
    __syncthreads();
#pragma unroll
    for (int i = 0; i < 4; ++i)
        out[(size_t)(bx * 32 + ty + i * 8) * D_IN + by * 32 + tx] = t[tx][ty + i * 8];
}

// ---------------- encode GEMM (screening, bf16 MFMA) ----------------
// zhat[r] (bf16) = bf16( Xb[r,:] @ Wb[c,:]^T + b_enc[c] ), written into the first
// 32KB of z_sparse row r's 64KB slot (row stride 16384 floats).
__global__ __launch_bounds__(256) void gemm_enc(const unsigned short* __restrict__ Xb,
                                                const unsigned short* __restrict__ Wb,
                                                const float* __restrict__ bEnc,
                                                float* __restrict__ zbase) {
    __shared__ unsigned short As[128 * 64];
    __shared__ unsigned short Bs[128 * 64];
    const int tid    = threadIdx.x;
    const int waveId = tid >> 6;
    const int lane   = tid & 63;
    const int rowBase = blockIdx.y * 128;
    const int colBase = blockIdx.x * 128;
    const int wm = waveId >> 1, wn = waveId & 1;

    f32x4 acc[4][4] = {};

    const int m0 = wm * 64 + (lane & 15);
    const int n0 = wn * 64 + (lane & 15);
    const int kq = (lane >> 4) * 8;

    for (int k0 = 0; k0 < D_IN; k0 += 64) {
#pragma unroll
        for (int i = 0; i < 4; ++i) {
            int slot = i * 256 + tid;
            int r = slot >> 3, cc = (slot & 7) * 8;
            const unsigned short* ga = Xb + (size_t)(rowBase + r) * D_IN + k0 + cc;
            const unsigned short* gb = Wb + (size_t)(colBase + r) * D_IN + k0 + cc;
            unsigned short* la = As + (size_t)(i * 256 + waveId * 64) * 8; // wave-uniform base
            unsigned short* lb = Bs + (size_t)(i * 256 + waveId * 64) * 8;
            gload_lds16(ga, la);
            gload_lds16(gb, lb);
        }
        __syncthreads();
#pragma unroll
        for (int kk = 0; kk < 64; kk += 32) {
            s16x8 a[4], b[4];
#pragma unroll
            for (int t = 0; t < 4; ++t) {
                a[t] = *(const s16x8*)(As + (m0 + t * 16) * 64 + kk + kq);
                b[t] = *(const s16x8*)(Bs + (n0 + t * 16) * 64 + kk + kq);
            }
#pragma unroll
            for (int mi = 0; mi < 4; ++mi)
#pragma unroll
                for (int ni = 0; ni < 4; ++ni)
                    acc[mi][ni] = __builtin_amdgcn_mfma_f32_16x16x32_bf16(
                        a[mi], b[ni], acc[mi][ni], 0, 0, 0);
        }
        __syncthreads();
    }

    // epilogue: C/D layout col=lane&15, row=(lane>>4)*4+reg
    const int col0 = colBase + wn * 64 + (lane & 15);
    const int rq   = (lane >> 4) * 4;
#pragma unroll
    for (int ni = 0; ni < 4; ++ni) {
        int gc = col0 + ni * 16;
        float bias = bEnc[gc];
#pragma unroll
        for (int mi = 0; mi < 4; ++mi) {
            int gr0 = rowBase + wm * 64 + mi * 16 + rq;
#pragma unroll
            for (int rg = 0; rg < 4; ++rg) {
                float v = acc[mi][ni][rg] + bias;
                ((unsigned short*)(zbase + (size_t)(gr0 + rg) * D_DICT))[gc] = f2bf(v);
            }
        }
    }
}

// ---------------- per-row: radix-select candidates -> fp64 refine -> exact top-32
//                  -> scatter z_sparse + fused decode ----------------
__global__ __launch_bounds__(256) void rowpass(const float* __restrict__ x,
                                               const float* __restrict__ wEnc,
                                               const float* __restrict__ bEnc,
                                               const float* __restrict__ bDec,
                                               const float* __restrict__ wDecT,
                                               float* __restrict__ xhat,
                                               float* __restrict__ zsp) {
    const int row = blockIdx.x;
    const int tid = threadIdx.x;

    __shared__ unsigned short zrow[D_DICT];   // 32 KB, order-mapped u16
    __shared__ int   hist[256];
    __shared__ float xs[D_IN];
    __shared__ int   cidx[CAND_MAX];
    __shared__ float zc[CAND_MAX];
    __shared__ int   selk[TOPK];
    __shared__ float selv[TOPK];
    __shared__ int   sh_nstrict, sh_ntie, sh_nsel, sh_cutHi, sh_cumAbove, sh_cut;

    hist[tid] = 0;
    if (tid == 0) { sh_nstrict = 0; sh_ntie = 0; sh_nsel = 0; }
    __syncthreads();

    // load zhat row (bf16 bits), map to order-preserving u16, histogram high byte
    const unsigned short* zr = (const unsigned short*)(zsp + (size_t)row * D_DICT);
#pragma unroll 2
    for (int i = 0; i < 8; ++i) {
        uint4 raw = ((const uint4*)zr)[i * 256 + tid];
        unsigned int w[4] = {raw.x, raw.y, raw.z, raw.w};
        int base = (i * 256 + tid) * 8;
#pragma unroll
        for (int q = 0; q < 4; ++q) {
#pragma unroll
            for (int h = 0; h < 2; ++h) {
                unsigned short u = (unsigned short)((w[q] >> (16 * h)) & 0xFFFFu);
                u = (u & 0x8000u) ? (unsigned short)(~u) : (unsigned short)(u | 0x8000u);
                zrow[base + q * 2 + h] = u;
                atomicAdd(&hist[u >> 8], 1);
            }
        }
    }
    for (int j = tid; j < D_IN; j += 256) xs[j] = x[(size_t)row * D_IN + j];
    __syncthreads();

    // zero this row of z_sparse (we own it; scatter happens after later barriers)
    {
        float4 z4 = make_float4(0.f, 0.f, 0.f, 0.f);
        float4* zd = (float4*)(zsp + (size_t)row * D_DICT);
#pragma unroll 4
        for (int i = 0; i < 16; ++i) zd[i * 256 + tid] = z4;
    }

    if (tid == 0) {  // find high-byte bin containing rank CAND_TARGET (from top)
        int cum = 0, b = 255;
        for (; b >= 0; --b) {
            int c = cum + hist[b];
            if (c >= CAND_TARGET) break;
            cum = c;
        }
        sh_cutHi = b; sh_cumAbove = cum;
    }
    __syncthreads();
    const int cutHi = sh_cutHi;
    hist[tid] = 0;
    __syncthreads();
    for (int i = 0; i < 64; ++i) {  // low-byte histogram inside cut bin
        unsigned short u = zrow[i * 256 + tid];
        if ((u >> 8) == cutHi) atomicAdd(&hist[u & 255], 1);
    }
    __syncthreads();
    if (tid == 0) {
        int cum = sh_cumAbove, b = 255;
        for (; b >= 0; --b) {
            int c = cum + hist[b];
            if (c >= CAND_TARGET) break;
            cum = c;
        }
        sh_cut = (cutHi << 8) | b;
    }
    __syncthreads();
    const unsigned short cut = (unsigned short)sh_cut;

    // collect candidates: strict > cut in front, ties == cut from the back
    for (int i = 0; i < 64; ++i) {
        int idx = i * 256 + tid;
        unsigned short u = zrow[idx];
        if (u > cut) {
            int p = atomicAdd(&sh_nstrict, 1);   // guaranteed < CAND_TARGET
            cidx[p] = idx;
        } else if (u == cut) {
            int t = atomicAdd(&sh_ntie, 1);
            if (t < CAND_TARGET) cidx[CAND_MAX - 1 - t] = idx;
        }
    }
    __syncthreads();
    const int nstrict = sh_nstrict;
    const int nt = min(sh_ntie, CAND_TARGET);
    int tmpv = 0;
    if (tid < nt) tmpv = cidx[CAND_MAX - 1 - tid];
    __syncthreads();
    if (tid < nt) cidx[nstrict + tid] = tmpv;
    __syncthreads();
    const int nc = nstrict + nt;   // >= CAND_TARGET >= 32

    // fp64-exact refinement of candidate dot products
    const int wave = tid >> 6, lane = tid & 63;
    for (int c = wave; c < nc; c += 4) {
        int k = cidx[c];
        const float* w = wEnc + (size_t)k * D_IN;
        double acc = 0.0;
#pragma unroll
        for (int i = 0; i < D_IN / 64; ++i) {
            int j = i * 64 + lane;
            acc += (double)xs[j] * (double)w[j];
        }
#pragma unroll
        for (int off = 32; off > 0; off >>= 1) acc += __shfl_xor(acc, off, 64);
        if (lane == 0) zc[c] = (float)(acc + (double)bEnc[k]);
    }
    __syncthreads();

    // exact rank among candidates (fp32 values, lower-index tie-break) -> top-32
    if (tid < nc) {
        float v = zc[tid];
        int   k = cidx[tid];
        int r = 0;
        for (int j = 0; j < nc; ++j) {
            float vj = zc[j];
            if (vj > v || (vj == v && cidx[j] < k)) ++r;
        }
        if (r < TOPK) {
            int s = atomicAdd(&sh_nsel, 1);
            selk[s] = k; selv[s] = v;
            zsp[(size_t)row * D_DICT + k] = v;
        }
    }
    __syncthreads();

    // fused decode: x_hat[row] = sum_j selv[j] * W_decT[selk[j], :] + b_dec
    for (int d = tid; d < D_IN; d += 256) {
        float acc = bDec[d];
#pragma unroll
        for (int j = 0; j < TOPK; ++j)
            acc += selv[j] * wDecT[(size_t)selk[j] * D_IN + d];
        xhat[(size_t)row * D_IN + d] = acc;
    }
}

extern "C" void kernel_launch(void* const* d_in, const int* in_sizes, int n_in,
                              void* d_out, int out_size, void* d_ws, size_t ws_size,
                              hipStream_t stream) {
    const float* x    = (const float*)d_in[0];
    const float* wEnc = (const float*)d_in[1];
    const float* bEnc = (const float*)d_in[2];
    const float* wDec = (const float*)d_in[3];
    const float* bDec = (const float*)d_in[4];

    float* xhat = (float*)d_out;                          // [8192][768]
    float* zsp  = (float*)d_out + (size_t)NROWS * D_IN;   // [8192][16384]

    char* ws = (char*)d_ws;
    unsigned short* Xb  = (unsigned short*)ws;                                  // 12.6 MB
    unsigned short* Wb  = (unsigned short*)(ws + (size_t)NROWS * D_IN * 2);     // 25.2 MB
    float*          WdT = (float*)(ws + (size_t)NROWS * D_IN * 2
                                      + (size_t)D_DICT * D_IN * 2);             // 50.3 MB

    {
        int n4 = NROWS * D_IN / 4;
        cast_bf16<<<(n4 + 255) / 256, 256, 0, stream>>>((const float4*)x, (u16x4*)Xb, n4);
    }
    {
        int n4 = D_DICT * D_IN / 4;
        cast_bf16<<<(n4 + 255) / 256, 256, 0, stream>>>((const float4*)wEnc, (u16x4*)Wb, n4);
    }
    transpose_wdec<<<dim3(D_DICT / 32, D_IN / 32), dim3(32, 8), 0, stream>>>(wDec, WdT);
    gemm_enc<<<dim3(D_DICT / 128, NROWS / 128), 256, 0, stream>>>(Xb, Wb, bEnc, zsp);
    rowpass<<<NROWS, 256, 0, stream>>>(x, wEnc, bEnc, bDec, WdT, xhat, zsp);
}

// Round 2
// 1351.961 us; speedup vs baseline: 1.0331x; 1.0331x over previous
//
#include <hip/hip_runtime.h>
#include <stdint.h>

#define D_IN   768
#define D_DICT 16384
#define NROWS  8192
#define TOPK   32
#define CAND_TARGET 40   // screening candidate count (bf16 noise << rank-40 margin)
#define CAND_MAX    80   // strict hits in [0,40), ties packed from slot 79 down

typedef __attribute__((ext_vector_type(4))) float  f32x4;
typedef __attribute__((ext_vector_type(8))) short  s16x8;
typedef __attribute__((ext_vector_type(4))) unsigned short u16x4;

static __device__ __forceinline__ unsigned short f2bf(float f) {
    unsigned int u = __float_as_uint(f);
    unsigned int r = (u + 0x7FFFu + ((u >> 16) & 1u)) >> 16;   // RNE
    return (unsigned short)r;
}
// order-preserving map: bf16 bits -> u16 (monotone in float order)
static __device__ __forceinline__ unsigned short bfmap(unsigned short u) {
    return (u & 0x8000u) ? (unsigned short)(~u) : (unsigned short)(u | 0x8000u);
}

static __device__ __forceinline__ void gload_lds16(const void* g, void* l) {
    __builtin_amdgcn_global_load_lds(
        (const __attribute__((address_space(1))) unsigned int*)g,
        (__attribute__((address_space(3))) unsigned int*)l, 16, 0, 0);
}

// ---------------- prep: fp32 -> bf16 cast (vectorized) ----------------
__global__ __launch_bounds__(256) void cast_bf16(const float4* __restrict__ in,
                                                 u16x4* __restrict__ out, int n4) {
    int idx = blockIdx.x * 256 + threadIdx.x;
    if (idx >= n4) return;
    float4 v = in[idx];
    u16x4 o;
    o.x = f2bf(v.x); o.y = f2bf(v.y); o.z = f2bf(v.z); o.w = f2bf(v.w);
    out[idx] = o;
}

// ---------------- prep: transpose W_dec [768][16384] -> [16384][768] ----------------
__global__ void transpose_wdec(const float* __restrict__ in, float* __restrict__ out) {
    __shared__ float t[32][33];
    int bx = blockIdx.x, by = blockIdx.y;
    int tx = threadIdx.x, ty = threadIdx.y;
#pragma unroll
    for (int i = 0; i < 4; ++i)
        t[ty + i * 8][tx] = in[(size_t)(by * 32 + ty + i * 8) * D_DICT + bx * 32 + tx];
    __syncthreads();
#pragma unroll
    for (int i = 0; i < 4; ++i)
        out[(size_t)(bx * 32 + ty + i * 8) * D_IN + by * 32 + tx] = t[tx][ty + i * 8];
}

// ---------------- encode GEMM (screening, bf16 MFMA) ----------------
// writes order-mapped u16 zhat[8192][16384] (contiguous) into first half of z region
__global__ __launch_bounds__(256) void gemm_enc(const unsigned short* __restrict__ Xb,
                                                const unsigned short* __restrict__ Wb,
                                                const float* __restrict__ bEnc,
                                                unsigned short* __restrict__ zhat) {
    __shared__ unsigned short As[128 * 64];
    __shared__ unsigned short Bs[128 * 64];
    const int tid    = threadIdx.x;
    const int waveId = tid >> 6;
    const int lane   = tid & 63;
    const int rowBase = blockIdx.y * 128;
    const int colBase = blockIdx.x * 128;
    const int wm = waveId >> 1, wn = waveId & 1;

    f32x4 acc[4][4] = {};

    const int m0 = wm * 64 + (lane & 15);
    const int n0 = wn * 64 + (lane & 15);
    const int kq = (lane >> 4) * 8;

    for (int k0 = 0; k0 < D_IN; k0 += 64) {
#pragma unroll
        for (int i = 0; i < 4; ++i) {
            int slot = i * 256 + tid;
            int r = slot >> 3, cc = (slot & 7) * 8;
            const unsigned short* ga = Xb + (size_t)(rowBase + r) * D_IN + k0 + cc;
            const unsigned short* gb = Wb + (size_t)(colBase + r) * D_IN + k0 + cc;
            unsigned short* la = As + (size_t)(i * 256 + waveId * 64) * 8;
            unsigned short* lb = Bs + (size_t)(i * 256 + waveId * 64) * 8;
            gload_lds16(ga, la);
            gload_lds16(gb, lb);
        }
        __syncthreads();
#pragma unroll
        for (int kk = 0; kk < 64; kk += 32) {
            s16x8 a[4], b[4];
#pragma unroll
            for (int t = 0; t < 4; ++t) {
                a[t] = *(const s16x8*)(As + (m0 + t * 16) * 64 + kk + kq);
                b[t] = *(const s16x8*)(Bs + (n0 + t * 16) * 64 + kk + kq);
            }
#pragma unroll
            for (int mi = 0; mi < 4; ++mi)
#pragma unroll
                for (int ni = 0; ni < 4; ++ni)
                    acc[mi][ni] = __builtin_amdgcn_mfma_f32_16x16x32_bf16(
                        a[mi], b[ni], acc[mi][ni], 0, 0, 0);
        }
        __syncthreads();
    }

    const int col0 = colBase + wn * 64 + (lane & 15);
    const int rq   = (lane >> 4) * 4;
#pragma unroll
    for (int ni = 0; ni < 4; ++ni) {
        int gc = col0 + ni * 16;
        float bias = bEnc[gc];
#pragma unroll
        for (int mi = 0; mi < 4; ++mi) {
            int gr0 = rowBase + wm * 64 + mi * 16 + rq;
#pragma unroll
            for (int rg = 0; rg < 4; ++rg) {
                float v = acc[mi][ni][rg] + bias;
                zhat[(size_t)(gr0 + rg) * D_DICT + gc] = bfmap(f2bf(v));
            }
        }
    }
}

// ---------------- selection kernel: 1 row/block, registers + light LDS ----------------
__global__ __launch_bounds__(256) void sel_topk(const unsigned short* __restrict__ zhat,
                                                const float* __restrict__ x,
                                                const float* __restrict__ wEnc,
                                                const float* __restrict__ bEnc,
                                                int* __restrict__ SelK,
                                                float* __restrict__ SelV) {
    const int row = blockIdx.x;
    const int tid = threadIdx.x;
    const int waveId = tid >> 6;

    __shared__ int   histc[4][256];    // per-wave histogram copies
    __shared__ float xs[D_IN];
    __shared__ int   cidx[CAND_MAX];
    __shared__ float zc[CAND_MAX];
    __shared__ int   selk[TOPK];
    __shared__ float selv[TOPK];
    __shared__ int   sh_bin, sh_cum, sh_bin2;
    __shared__ int   sh_nstrict, sh_ntie, sh_nsel;

    // load this row's 64 screened values into registers
    uint4 r[8];
    const uint4* zr4 = (const uint4*)(zhat + (size_t)row * D_DICT);
#pragma unroll
    for (int i = 0; i < 8; ++i) r[i] = zr4[i * 256 + tid];
    for (int j = tid; j < D_IN; j += 256) xs[j] = x[(size_t)row * D_IN + j];
    if (tid == 0) { sh_nstrict = 0; sh_ntie = 0; sh_nsel = 0; }

    // -------- two-level radix cut with static floor + fallback --------
    unsigned int floorU = 0xBE80u;  // mapped bf16(0.25); ~33% of elems pass
    int shift1 = 6;                 // 64-code coarse bins over top range
    const int T = CAND_TARGET;

    for (int att = 0; att < 2; ++att) {
        for (int b = tid; b < 1024; b += 256) ((int*)histc)[b] = 0;
        if (tid == 0) sh_bin = -1;
        __syncthreads();
#pragma unroll
        for (int i = 0; i < 8; ++i) {
            unsigned int w[4] = {r[i].x, r[i].y, r[i].z, r[i].w};
#pragma unroll
            for (int q = 0; q < 4; ++q)
#pragma unroll
                for (int h = 0; h < 2; ++h) {
                    unsigned int u = (w[q] >> (16 * h)) & 0xFFFFu;
                    if (u >= floorU) {
                        int bin = (int)((u - floorU) >> shift1);
                        if (bin > 255) bin = 255;
                        atomicAdd(&histc[waveId][bin], 1);
                    }
                }
        }
        __syncthreads();
        if (tid < 256) histc[0][tid] += histc[1][tid] + histc[2][tid] + histc[3][tid];
        __syncthreads();
        if (tid < 64) {  // wave-0 descending prefix scan over 256 bins
            int l = tid;
            int b0 = 255 - l * 4;
            int s0 = histc[0][b0], s1 = histc[0][b0 - 1],
                s2 = histc[0][b0 - 2], s3 = histc[0][b0 - 3];
            int local = s0 + s1 + s2 + s3;
            int pref = local;
#pragma unroll
            for (int off = 1; off < 64; off <<= 1) {
                int n = __shfl_up(pref, off, 64);
                if (l >= off) pref += n;
            }
            unsigned long long m = __ballot(pref >= T);
            if (m) {
                int first = (int)__ffsll(m) - 1;
                if (l == first) {
                    int cum = pref - local;
                    int b, c;
                    if      (cum + s0 >= T)           { b = b0;     c = cum; }
                    else if (cum + s0 + s1 >= T)      { b = b0 - 1; c = cum + s0; }
                    else if (cum + s0 + s1 + s2 >= T) { b = b0 - 2; c = cum + s0 + s1; }
                    else                              { b = b0 - 3; c = cum + s0 + s1 + s2; }
                    sh_bin = b; sh_cum = c;
                }
            }
        }
        __syncthreads();
        if (sh_bin >= 0) break;
        floorU = 0u; shift1 = 8;   // fallback: full-range histogram (unreachable in practice)
    }
    const int b1 = sh_bin;
    const int cumAbove = sh_cum;
    const int s2 = shift1 - 6;     // 64 sub-bins

    // -------- fine pass within coarse bin b1 --------
    for (int b = tid; b < 1024; b += 256) ((int*)histc)[b] = 0;
    __syncthreads();
#pragma unroll
    for (int i = 0; i < 8; ++i) {
        unsigned int w[4] = {r[i].x, r[i].y, r[i].z, r[i].w};
#pragma unroll
        for (int q = 0; q < 4; ++q)
#pragma unroll
            for (int h = 0; h < 2; ++h) {
                unsigned int u = (w[q] >> (16 * h)) & 0xFFFFu;
                if (u >= floorU) {
                    int bin = (int)((u - floorU) >> shift1);
                    if (bin > 255) bin = 255;
                    if (bin == b1) {
                        int bin2 = (int)(((u - floorU) >> s2) & 63u);
                        atomicAdd(&histc[waveId][bin2], 1);
                    }
                }
            }
    }
    __syncthreads();
    if (tid < 64) {  // wave-0 descending scan over 64 sub-bins
        int l = tid;
        int bb = 63 - l;
        int local = histc[0][bb] + histc[1][bb] + histc[2][bb] + histc[3][bb];
        int pref = local;
#pragma unroll
        for (int off = 1; off < 64; off <<= 1) {
            int n = __shfl_up(pref, off, 64);
            if (l >= off) pref += n;
        }
        unsigned long long m = __ballot(cumAbove + pref >= T);
        int first = (int)__ffsll(m) - 1;
        if (l == first) sh_bin2 = bb;
    }
    __syncthreads();
    const unsigned int tieLo  = floorU + ((unsigned)b1 << shift1) + ((unsigned)sh_bin2 << s2);
    const unsigned int tieTop = tieLo + (1u << s2) - 1u;

    // -------- collect candidates from registers --------
#pragma unroll
    for (int i = 0; i < 8; ++i) {
        unsigned int w[4] = {r[i].x, r[i].y, r[i].z, r[i].w};
#pragma unroll
        for (int q = 0; q < 4; ++q)
#pragma unroll
            for (int h = 0; h < 2; ++h) {
                unsigned int u = (w[q] >> (16 * h)) & 0xFFFFu;
                if (u > tieTop) {
                    int p = atomicAdd(&sh_nstrict, 1);   // < CAND_TARGET guaranteed
                    cidx[p] = (i * 256 + tid) * 8 + q * 2 + h;
                } else if (u >= tieLo) {
                    int t = atomicAdd(&sh_ntie, 1);
                    if (t < CAND_TARGET) cidx[CAND_MAX - 1 - t] = (i * 256 + tid) * 8 + q * 2 + h;
                }
            }
    }
    __syncthreads();
    const int nstrict = sh_nstrict;
    const int nt = min(sh_ntie, CAND_TARGET);
    int tmpv = 0;
    if (tid < nt) tmpv = cidx[CAND_MAX - 1 - tid];
    __syncthreads();
    if (tid < nt) cidx[nstrict + tid] = tmpv;
    __syncthreads();
    const int nc = nstrict + nt;   // in [CAND_TARGET, CAND_MAX)

    // -------- fp64-exact refinement: 4 lanes per candidate --------
    const int sub = tid & 3;
    const int cq  = tid >> 2;
    for (int c0 = 0; c0 < nc; c0 += 64) {
        int c = c0 + cq;
        double acc = 0.0;
        int k = 0;
        if (c < nc) {
            k = cidx[c];
            const float* w  = wEnc + (size_t)k * D_IN + sub * 192;
            const float* xp = xs + sub * 192;
#pragma unroll 8
            for (int j = 0; j < 192; ++j) acc += (double)xp[j] * (double)w[j];
        }
        acc += __shfl_xor(acc, 1, 64);
        acc += __shfl_xor(acc, 2, 64);
        if (c < nc && sub == 0) zc[c] = (float)(acc + (double)bEnc[k]);
    }
    __syncthreads();

    // -------- exact rank (fp32 values, lower-index tie-break) -> top-32 --------
    if (tid < nc) {
        float v = zc[tid];
        int   k = cidx[tid];
        int rk = 0;
        for (int j = 0; j < nc; ++j) {
            float vj = zc[j];
            if (vj > v || (vj == v && cidx[j] < k)) ++rk;
        }
        if (rk < TOPK) {
            int s = atomicAdd(&sh_nsel, 1);
            selk[s] = k; selv[s] = v;
        }
    }
    __syncthreads();
    if (tid < TOPK) {
        SelK[(size_t)row * TOPK + tid] = selk[tid];
        SelV[(size_t)row * TOPK + tid] = selv[tid];
    }
}

// ---------------- zero + scatter + fused decode: 1 row/block ----------------
__global__ __launch_bounds__(256) void zdec(const int* __restrict__ SelK,
                                            const float* __restrict__ SelV,
                                            const float* __restrict__ wDecT,
                                            const float* __restrict__ bDec,
                                            float* __restrict__ zsp,
                                            float* __restrict__ xhat) {
    const int row = blockIdx.x;
    const int tid = threadIdx.x;
    __shared__ int   sk[TOPK];
    __shared__ float sv[TOPK];
    if (tid < TOPK) {
        sk[tid] = SelK[(size_t)row * TOPK + tid];
        sv[tid] = SelV[(size_t)row * TOPK + tid];
    }
    // zero the full z row (64 KB)
    float4 z4 = make_float4(0.f, 0.f, 0.f, 0.f);
    float4* zd = (float4*)(zsp + (size_t)row * D_DICT);
#pragma unroll
    for (int i = 0; i < 16; ++i) zd[i * 256 + tid] = z4;
    __syncthreads();   // all zero-stores drained (vmcnt(0)) before scatter
    if (tid < TOPK) zsp[(size_t)row * D_DICT + sk[tid]] = sv[tid];

    // decode: x_hat[row] = sum_j sv[j] * W_decT[sk[j], :] + b_dec
    for (int d = tid; d < D_IN; d += 256) {
        float acc = bDec[d];
#pragma unroll
        for (int j = 0; j < TOPK; ++j)
            acc += sv[j] * wDecT[(size_t)sk[j] * D_IN + d];
        xhat[(size_t)row * D_IN + d] = acc;
    }
}

extern "C" void kernel_launch(void* const* d_in, const int* in_sizes, int n_in,
                              void* d_out, int out_size, void* d_ws, size_t ws_size,
                              hipStream_t stream) {
    const float* x    = (const float*)d_in[0];
    const float* wEnc = (const float*)d_in[1];
    const float* bEnc = (const float*)d_in[2];
    const float* wDec = (const float*)d_in[3];
    const float* bDec = (const float*)d_in[4];

    float* xhat = (float*)d_out;                          // [8192][768]
    float* zsp  = (float*)d_out + (size_t)NROWS * D_IN;   // [8192][16384]
    unsigned short* zhat = (unsigned short*)zsp;          // u16[8192][16384], first half of z region

    char* ws = (char*)d_ws;
    unsigned short* Xb  = (unsigned short*)ws;                                  // 12.6 MB
    unsigned short* Wb  = (unsigned short*)(ws + (size_t)NROWS * D_IN * 2);     // 25.2 MB
    float*          WdT = (float*)(ws + (size_t)NROWS * D_IN * 2
                                      + (size_t)D_DICT * D_IN * 2);             // 50.3 MB
    int*   SelK = (int*)(ws + 88080384);                                        // 1 MB
    float* SelV = (float*)(ws + 88080384 + (size_t)NROWS * TOPK * 4);           // 1 MB

    {
        int n4 = NROWS * D_IN / 4;
        cast_bf16<<<(n4 + 255) / 256, 256, 0, stream>>>((const float4*)x, (u16x4*)Xb, n4);
    }
    {
        int n4 = D_DICT * D_IN / 4;
        cast_bf16<<<(n4 + 255) / 256, 256, 0, stream>>>((const float4*)wEnc, (u16x4*)Wb, n4);
    }
    transpose_wdec<<<dim3(D_DICT / 32, D_IN / 32), dim3(32, 8), 0, stream>>>(wDec, WdT);
    gemm_enc<<<dim3(D_DICT / 128, NROWS / 128), 256, 0, stream>>>(Xb, Wb, bEnc, zhat);
    sel_topk<<<NROWS, 256, 0, stream>>>(zhat, x, wEnc, bEnc, SelK, SelV);
    zdec<<<NROWS, 256, 0, stream>>>(SelK, SelV, WdT, bDec, zsp, xhat);
}

// Round 3
// 1319.564 us; speedup vs baseline: 1.0584x; 1.0246x over previous
//
#include <hip/hip_runtime.h>
#include <stdint.h>

#define D_IN   768
#define D_DICT 16384
#define NROWS  8192
#define TOPK   32
#define CAND_TARGET 40   // screening candidate count (bf16 noise << rank-40 margin)
#define CAND_MAX    80   // strict hits in [0,40), ties packed from slot 79 down

typedef __attribute__((ext_vector_type(4))) float  f32x4;
typedef __attribute__((ext_vector_type(8))) short  s16x8;
typedef __attribute__((ext_vector_type(4))) unsigned short u16x4;

static __device__ __forceinline__ unsigned short f2bf(float f) {
    unsigned int u = __float_as_uint(f);
    unsigned int r = (u + 0x7FFFu + ((u >> 16) & 1u)) >> 16;   // RNE
    return (unsigned short)r;
}
// order-preserving map: bf16 bits -> u16 (monotone in float order)
static __device__ __forceinline__ unsigned short bfmap(unsigned short u) {
    return (u & 0x8000u) ? (unsigned short)(~u) : (unsigned short)(u | 0x8000u);
}

static __device__ __forceinline__ void gload_lds16(const void* g, void* l) {
    __builtin_amdgcn_global_load_lds(
        (const __attribute__((address_space(1))) unsigned int*)g,
        (__attribute__((address_space(3))) unsigned int*)l, 16, 0, 0);
}

// ---------------- prep: fp32 -> bf16 cast (vectorized) ----------------
__global__ __launch_bounds__(256) void cast_bf16(const float4* __restrict__ in,
                                                 u16x4* __restrict__ out, int n4) {
    int idx = blockIdx.x * 256 + threadIdx.x;
    if (idx >= n4) return;
    float4 v = in[idx];
    u16x4 o;
    o.x = f2bf(v.x); o.y = f2bf(v.y); o.z = f2bf(v.z); o.w = f2bf(v.w);
    out[idx] = o;
}

// ---------------- prep: transpose W_dec [768][16384] -> [16384][768] ----------------
__global__ void transpose_wdec(const float* __restrict__ in, float* __restrict__ out) {
    __shared__ float t[32][33];
    int bx = blockIdx.x, by = blockIdx.y;
    int tx = threadIdx.x, ty = threadIdx.y;
#pragma unroll
    for (int i = 0; i < 4; ++i)
        t[ty + i * 8][tx] = in[(size_t)(by * 32 + ty + i * 8) * D_DICT + bx * 32 + tx];
    __syncthreads();
#pragma unroll
    for (int i = 0; i < 4; ++i)
        out[(size_t)(bx * 32 + ty + i * 8) * D_IN + by * 32 + tx] = t[tx][ty + i * 8];
}

// ---------------- encode GEMM (screening, bf16 MFMA) ----------------
// LDS tiles XOR-swizzled: row r's logical chunk c (16B) lives at physical chunk c^(r&7).
// global_load_lds dest is fixed (base+lane*16), so the swizzle is applied to the
// per-lane GLOBAL source address; read side XORs with (row&7) == (lane&7).
__global__ __launch_bounds__(256) void gemm_enc(const unsigned short* __restrict__ Xb,
                                                const unsigned short* __restrict__ Wb,
                                                const float* __restrict__ bEnc,
                                                unsigned short* __restrict__ zhat) {
    __shared__ unsigned short As[128 * 64];
    __shared__ unsigned short Bs[128 * 64];
    const int tid    = threadIdx.x;
    const int waveId = tid >> 6;
    const int lane   = tid & 63;
    const int rowBase = blockIdx.y * 128;
    const int colBase = blockIdx.x * 128;
    const int wm = waveId >> 1, wn = waveId & 1;

    f32x4 acc[4][4] = {};

    const int m0 = wm * 64 + (lane & 15);
    const int n0 = wn * 64 + (lane & 15);
    const int quad = lane >> 4;          // 0..3
    const int xa = m0 & 7;               // read-side XOR factor (== lane&7)
    const int xb = n0 & 7;

    for (int k0 = 0; k0 < D_IN; k0 += 64) {
#pragma unroll
        for (int i = 0; i < 4; ++i) {
            int slot = i * 256 + tid;
            int r = slot >> 3;
            int cc = ((slot & 7) ^ (r & 7)) * 8;     // swizzled source chunk
            const unsigned short* ga = Xb + (size_t)(rowBase + r) * D_IN + k0 + cc;
            const unsigned short* gb = Wb + (size_t)(colBase + r) * D_IN + k0 + cc;
            unsigned short* la = As + (size_t)(i * 256 + waveId * 64) * 8;
            unsigned short* lb = Bs + (size_t)(i * 256 + waveId * 64) * 8;
            gload_lds16(ga, la);
            gload_lds16(gb, lb);
        }
        __syncthreads();
#pragma unroll
        for (int kk = 0; kk < 2; ++kk) {             // two 32-wide k-steps
            const int ch = kk * 4 + quad;            // logical chunk 0..7
            s16x8 a[4], b[4];
#pragma unroll
            for (int t = 0; t < 4; ++t) {
                a[t] = *(const s16x8*)(As + (m0 + t * 16) * 64 + ((ch ^ xa) << 3));
                b[t] = *(const s16x8*)(Bs + (n0 + t * 16) * 64 + ((ch ^ xb) << 3));
            }
#pragma unroll
            for (int mi = 0; mi < 4; ++mi)
#pragma unroll
                for (int ni = 0; ni < 4; ++ni)
                    acc[mi][ni] = __builtin_amdgcn_mfma_f32_16x16x32_bf16(
                        a[mi], b[ni], acc[mi][ni], 0, 0, 0);
        }
        __syncthreads();
    }

    const int col0 = colBase + wn * 64 + (lane & 15);
    const int rq   = (lane >> 4) * 4;
#pragma unroll
    for (int ni = 0; ni < 4; ++ni) {
        int gc = col0 + ni * 16;
        float bias = bEnc[gc];
#pragma unroll
        for (int mi = 0; mi < 4; ++mi) {
            int gr0 = rowBase + wm * 64 + mi * 16 + rq;
#pragma unroll
            for (int rg = 0; rg < 4; ++rg) {
                float v = acc[mi][ni][rg] + bias;
                zhat[(size_t)(gr0 + rg) * D_DICT + gc] = bfmap(f2bf(v));
            }
        }
    }
}

// ---------------- selection kernel: 1 row/block, registers + light LDS ----------------
__global__ __launch_bounds__(256) void sel_topk(const unsigned short* __restrict__ zhat,
                                                const float* __restrict__ x,
                                                const float* __restrict__ wEnc,
                                                const float* __restrict__ bEnc,
                                                int* __restrict__ SelK,
                                                float* __restrict__ SelV) {
    const int row = blockIdx.x;
    const int tid = threadIdx.x;
    const int waveId = tid >> 6;

    __shared__ int   histc[4][256];    // per-wave histogram copies
    __shared__ float xs[D_IN];
    __shared__ int   cidx[CAND_MAX];
    __shared__ float zc[CAND_MAX];
    __shared__ int   selk[TOPK];
    __shared__ float selv[TOPK];
    __shared__ int   sh_bin, sh_cum, sh_bin2;
    __shared__ int   sh_nstrict, sh_ntie, sh_nsel;

    // load this row's 64 screened values into registers
    uint4 r[8];
    const uint4* zr4 = (const uint4*)(zhat + (size_t)row * D_DICT);
#pragma unroll
    for (int i = 0; i < 8; ++i) r[i] = zr4[i * 256 + tid];
    for (int j = tid; j < D_IN; j += 256) xs[j] = x[(size_t)row * D_IN + j];
    if (tid == 0) { sh_nstrict = 0; sh_ntie = 0; sh_nsel = 0; }

    // -------- two-level radix cut with static floor + fallback --------
    unsigned int floorU = 0xBF80u;  // mapped bf16(1.0); ~4% of elems pass (rank-80 at z~1.5)
    int shift1 = 6;                 // 64-code coarse bins over top range
    const int T = CAND_TARGET;

    for (int att = 0; att < 2; ++att) {
        for (int b = tid; b < 1024; b += 256) ((int*)histc)[b] = 0;
        if (tid == 0) sh_bin = -1;
        __syncthreads();
#pragma unroll
        for (int i = 0; i < 8; ++i) {
            unsigned int w[4] = {r[i].x, r[i].y, r[i].z, r[i].w};
#pragma unroll
            for (int q = 0; q < 4; ++q)
#pragma unroll
                for (int h = 0; h < 2; ++h) {
                    unsigned int u = (w[q] >> (16 * h)) & 0xFFFFu;
                    if (u >= floorU) {
                        int bin = (int)((u - floorU) >> shift1);
                        if (bin > 255) bin = 255;
                        atomicAdd(&histc[waveId][bin], 1);
                    }
                }
        }
        __syncthreads();
        if (tid < 256) histc[0][tid] += histc[1][tid] + histc[2][tid] + histc[3][tid];
        __syncthreads();
        if (tid < 64) {  // wave-0 descending prefix scan over 256 bins
            int l = tid;
            int b0 = 255 - l * 4;
            int s0 = histc[0][b0], s1 = histc[0][b0 - 1],
                s2 = histc[0][b0 - 2], s3 = histc[0][b0 - 3];
            int local = s0 + s1 + s2 + s3;
            int pref = local;
#pragma unroll
            for (int off = 1; off < 64; off <<= 1) {
                int n = __shfl_up(pref, off, 64);
                if (l >= off) pref += n;
            }
            unsigned long long m = __ballot(pref >= T);
            if (m) {
                int first = (int)__ffsll(m) - 1;
                if (l == first) {
                    int cum = pref - local;
                    int b, c;
                    if      (cum + s0 >= T)           { b = b0;     c = cum; }
                    else if (cum + s0 + s1 >= T)      { b = b0 - 1; c = cum + s0; }
                    else if (cum + s0 + s1 + s2 >= T) { b = b0 - 2; c = cum + s0 + s1; }
                    else                              { b = b0 - 3; c = cum + s0 + s1 + s2; }
                    sh_bin = b; sh_cum = c;
                }
            }
        }
        __syncthreads();
        if (sh_bin >= 0) break;
        floorU = 0u; shift1 = 8;   // fallback: full-range histogram (unreachable in practice)
    }
    const int b1 = sh_bin;
    const int cumAbove = sh_cum;
    const int s2 = shift1 - 6;     // 64 sub-bins

    // -------- fine pass within coarse bin b1 --------
    for (int b = tid; b < 1024; b += 256) ((int*)histc)[b] = 0;
    __syncthreads();
#pragma unroll
    for (int i = 0; i < 8; ++i) {
        unsigned int w[4] = {r[i].x, r[i].y, r[i].z, r[i].w};
#pragma unroll
        for (int q = 0; q < 4; ++q)
#pragma unroll
            for (int h = 0; h < 2; ++h) {
                unsigned int u = (w[q] >> (16 * h)) & 0xFFFFu;
                if (u >= floorU) {
                    int bin = (int)((u - floorU) >> shift1);
                    if (bin > 255) bin = 255;
                    if (bin == b1) {
                        int bin2 = (int)(((u - floorU) >> s2) & 63u);
                        atomicAdd(&histc[waveId][bin2], 1);
                    }
                }
            }
    }
    __syncthreads();
    if (tid < 64) {  // wave-0 descending scan over 64 sub-bins
        int l = tid;
        int bb = 63 - l;
        int local = histc[0][bb] + histc[1][bb] + histc[2][bb] + histc[3][bb];
        int pref = local;
#pragma unroll
        for (int off = 1; off < 64; off <<= 1) {
            int n = __shfl_up(pref, off, 64);
            if (l >= off) pref += n;
        }
        unsigned long long m = __ballot(cumAbove + pref >= T);
        int first = (int)__ffsll(m) - 1;
        if (l == first) sh_bin2 = bb;
    }
    __syncthreads();
    const unsigned int tieLo  = floorU + ((unsigned)b1 << shift1) + ((unsigned)sh_bin2 << s2);
    const unsigned int tieTop = tieLo + (1u << s2) - 1u;

    // -------- collect candidates from registers --------
#pragma unroll
    for (int i = 0; i < 8; ++i) {
        unsigned int w[4] = {r[i].x, r[i].y, r[i].z, r[i].w};
#pragma unroll
        for (int q = 0; q < 4; ++q)
#pragma unroll
            for (int h = 0; h < 2; ++h) {
                unsigned int u = (w[q] >> (16 * h)) & 0xFFFFu;
                if (u > tieTop) {
                    int p = atomicAdd(&sh_nstrict, 1);   // < CAND_TARGET guaranteed
                    cidx[p] = (i * 256 + tid) * 8 + q * 2 + h;
                } else if (u >= tieLo) {
                    int t = atomicAdd(&sh_ntie, 1);
                    if (t < CAND_TARGET) cidx[CAND_MAX - 1 - t] = (i * 256 + tid) * 8 + q * 2 + h;
                }
            }
    }
    __syncthreads();
    const int nstrict = sh_nstrict;
    const int nt = min(sh_ntie, CAND_TARGET);
    int tmpv = 0;
    if (tid < nt) tmpv = cidx[CAND_MAX - 1 - tid];
    __syncthreads();
    if (tid < nt) cidx[nstrict + tid] = tmpv;
    __syncthreads();
    const int nc = nstrict + nt;   // in [CAND_TARGET, CAND_MAX)

    // -------- fp64-exact refinement: 4 lanes per candidate --------
    const int sub = tid & 3;
    const int cq  = tid >> 2;
    for (int c0 = 0; c0 < nc; c0 += 64) {
        int c = c0 + cq;
        double acc = 0.0;
        int k = 0;
        if (c < nc) {
            k = cidx[c];
            const float* w  = wEnc + (size_t)k * D_IN + sub * 192;
            const float* xp = xs + sub * 192;
#pragma unroll 8
            for (int j = 0; j < 192; ++j) acc += (double)xp[j] * (double)w[j];
        }
        acc += __shfl_xor(acc, 1, 64);
        acc += __shfl_xor(acc, 2, 64);
        if (c < nc && sub == 0) zc[c] = (float)(acc + (double)bEnc[k]);
    }
    __syncthreads();

    // -------- exact rank (fp32 values, lower-index tie-break) -> top-32 --------
    if (tid < nc) {
        float v = zc[tid];
        int   k = cidx[tid];
        int rk = 0;
        for (int j = 0; j < nc; ++j) {
            float vj = zc[j];
            if (vj > v || (vj == v && cidx[j] < k)) ++rk;
        }
        if (rk < TOPK) {
            int s = atomicAdd(&sh_nsel, 1);
            selk[s] = k; selv[s] = v;
        }
    }
    __syncthreads();
    if (tid < TOPK) {
        SelK[(size_t)row * TOPK + tid] = selk[tid];
        SelV[(size_t)row * TOPK + tid] = selv[tid];
    }
}

// ---------------- zero + scatter + fused decode: 1 row/block ----------------
__global__ __launch_bounds__(256) void zdec(const int* __restrict__ SelK,
                                            const float* __restrict__ SelV,
                                            const float* __restrict__ wDecT,
                                            const float* __restrict__ bDec,
                                            float* __restrict__ zsp,
                                            float* __restrict__ xhat) {
    const int row = blockIdx.x;
    const int tid = threadIdx.x;
    __shared__ int   sk[TOPK];
    __shared__ float sv[TOPK];
    if (tid < TOPK) {
        sk[tid] = SelK[(size_t)row * TOPK + tid];
        sv[tid] = SelV[(size_t)row * TOPK + tid];
    }
    // zero the full z row (64 KB)
    float4 z4 = make_float4(0.f, 0.f, 0.f, 0.f);
    float4* zd = (float4*)(zsp + (size_t)row * D_DICT);
#pragma unroll
    for (int i = 0; i < 16; ++i) zd[i * 256 + tid] = z4;
    __syncthreads();   // all zero-stores drained before scatter
    if (tid < TOPK) zsp[(size_t)row * D_DICT + sk[tid]] = sv[tid];

    // decode: x_hat[row] = sum_j sv[j] * W_decT[sk[j], :] + b_dec
    for (int d = tid; d < D_IN; d += 256) {
        float acc = bDec[d];
#pragma unroll
        for (int j = 0; j < TOPK; ++j)
            acc += sv[j] * wDecT[(size_t)sk[j] * D_IN + d];
        xhat[(size_t)row * D_IN + d] = acc;
    }
}

extern "C" void kernel_launch(void* const* d_in, const int* in_sizes, int n_in,
                              void* d_out, int out_size, void* d_ws, size_t ws_size,
                              hipStream_t stream) {
    const float* x    = (const float*)d_in[0];
    const float* wEnc = (const float*)d_in[1];
    const float* bEnc = (const float*)d_in[2];
    const float* wDec = (const float*)d_in[3];
    const float* bDec = (const float*)d_in[4];

    float* xhat = (float*)d_out;                          // [8192][768]
    float* zsp  = (float*)d_out + (size_t)NROWS * D_IN;   // [8192][16384]
    unsigned short* zhat = (unsigned short*)zsp;          // u16[8192][16384], first half of z region

    char* ws = (char*)d_ws;
    unsigned short* Xb  = (unsigned short*)ws;                                  // 12.6 MB
    unsigned short* Wb  = (unsigned short*)(ws + (size_t)NROWS * D_IN * 2);     // 25.2 MB
    float*          WdT = (float*)(ws + (size_t)NROWS * D_IN * 2
                                      + (size_t)D_DICT * D_IN * 2);             // 50.3 MB
    int*   SelK = (int*)(ws + 88080384);                                        // 1 MB
    float* SelV = (float*)(ws + 88080384 + (size_t)NROWS * TOPK * 4);           // 1 MB

    {
        int n4 = NROWS * D_IN / 4;
        cast_bf16<<<(n4 + 255) / 256, 256, 0, stream>>>((const float4*)x, (u16x4*)Xb, n4);
    }
    {
        int n4 = D_DICT * D_IN / 4;
        cast_bf16<<<(n4 + 255) / 256, 256, 0, stream>>>((const float4*)wEnc, (u16x4*)Wb, n4);
    }
    transpose_wdec<<<dim3(D_DICT / 32, D_IN / 32), dim3(32, 8), 0, stream>>>(wDec, WdT);
    gemm_enc<<<dim3(D_DICT / 128, NROWS / 128), 256, 0, stream>>>(Xb, Wb, bEnc, zhat);
    sel_topk<<<NROWS, 256, 0, stream>>>(zhat, x, wEnc, bEnc, SelK, SelV);
    zdec<<<NROWS, 256, 0, stream>>>(SelK, SelV, WdT, bDec, zsp, xhat);
}

// Round 4
// 1316.915 us; speedup vs baseline: 1.0606x; 1.0020x over previous
//
#include <hip/hip_runtime.h>
#include <stdint.h>

#define D_IN   768
#define D_DICT 16384
#define NROWS  8192
#define TOPK   32
#define CAND_TARGET 40   // screening candidate count (bf16 noise << rank-40 margin)
#define CAND_MAX    80   // strict hits in [0,40), ties packed from slot 79 down

typedef __attribute__((ext_vector_type(4))) float  f32x4;
typedef __attribute__((ext_vector_type(8))) short  s16x8;
typedef __attribute__((ext_vector_type(4))) unsigned short u16x4;

static __device__ __forceinline__ unsigned short f2bf(float f) {
    unsigned int u = __float_as_uint(f);
    unsigned int r = (u + 0x7FFFu + ((u >> 16) & 1u)) >> 16;   // RNE
    return (unsigned short)r;
}
// order-preserving map: bf16 bits -> u16 (monotone in float order)
static __device__ __forceinline__ unsigned short bfmap(unsigned short u) {
    return (u & 0x8000u) ? (unsigned short)(~u) : (unsigned short)(u | 0x8000u);
}

static __device__ __forceinline__ void gload_lds16(const void* g, void* l) {
    __builtin_amdgcn_global_load_lds(
        (const __attribute__((address_space(1))) unsigned int*)g,
        (__attribute__((address_space(3))) unsigned int*)l, 16, 0, 0);
}

// ---------------- prep: fp32 -> bf16 cast (vectorized) ----------------
__global__ __launch_bounds__(256) void cast_bf16(const float4* __restrict__ in,
                                                 u16x4* __restrict__ out, int n4) {
    int idx = blockIdx.x * 256 + threadIdx.x;
    if (idx >= n4) return;
    float4 v = in[idx];
    u16x4 o;
    o.x = f2bf(v.x); o.y = f2bf(v.y); o.z = f2bf(v.z); o.w = f2bf(v.w);
    out[idx] = o;
}

// ---------------- prep: transpose W_dec [768][16384] -> [16384][768] ----------------
__global__ void transpose_wdec(const float* __restrict__ in, float* __restrict__ out) {
    __shared__ float t[32][33];
    int bx = blockIdx.x, by = blockIdx.y;
    int tx = threadIdx.x, ty = threadIdx.y;
#pragma unroll
    for (int i = 0; i < 4; ++i)
        t[ty + i * 8][tx] = in[(size_t)(by * 32 + ty + i * 8) * D_DICT + bx * 32 + tx];
    __syncthreads();
#pragma unroll
    for (int i = 0; i < 4; ++i)
        out[(size_t)(bx * 32 + ty + i * 8) * D_IN + by * 32 + tx] = t[tx][ty + i * 8];
}

// ---------------- encode GEMM (screening, bf16 MFMA) ----------------
// LDS tiles XOR-swizzled: row r's logical chunk c (16B) lives at physical chunk c^(r&7).
__global__ __launch_bounds__(256) void gemm_enc(const unsigned short* __restrict__ Xb,
                                                const unsigned short* __restrict__ Wb,
                                                const float* __restrict__ bEnc,
                                                unsigned short* __restrict__ zhat) {
    __shared__ unsigned short As[128 * 64];
    __shared__ unsigned short Bs[128 * 64];
    const int tid    = threadIdx.x;
    const int waveId = tid >> 6;
    const int lane   = tid & 63;
    const int rowBase = blockIdx.y * 128;
    const int colBase = blockIdx.x * 128;
    const int wm = waveId >> 1, wn = waveId & 1;

    f32x4 acc[4][4] = {};

    const int m0 = wm * 64 + (lane & 15);
    const int n0 = wn * 64 + (lane & 15);
    const int quad = lane >> 4;          // 0..3
    const int xa = m0 & 7;               // read-side XOR factor
    const int xb = n0 & 7;

    for (int k0 = 0; k0 < D_IN; k0 += 64) {
#pragma unroll
        for (int i = 0; i < 4; ++i) {
            int slot = i * 256 + tid;
            int r = slot >> 3;
            int cc = ((slot & 7) ^ (r & 7)) * 8;     // swizzled source chunk
            const unsigned short* ga = Xb + (size_t)(rowBase + r) * D_IN + k0 + cc;
            const unsigned short* gb = Wb + (size_t)(colBase + r) * D_IN + k0 + cc;
            unsigned short* la = As + (size_t)(i * 256 + waveId * 64) * 8;
            unsigned short* lb = Bs + (size_t)(i * 256 + waveId * 64) * 8;
            gload_lds16(ga, la);
            gload_lds16(gb, lb);
        }
        __syncthreads();
#pragma unroll
        for (int kk = 0; kk < 2; ++kk) {             // two 32-wide k-steps
            const int ch = kk * 4 + quad;            // logical chunk 0..7
            s16x8 a[4], b[4];
#pragma unroll
            for (int t = 0; t < 4; ++t) {
                a[t] = *(const s16x8*)(As + (m0 + t * 16) * 64 + ((ch ^ xa) << 3));
                b[t] = *(const s16x8*)(Bs + (n0 + t * 16) * 64 + ((ch ^ xb) << 3));
            }
#pragma unroll
            for (int mi = 0; mi < 4; ++mi)
#pragma unroll
                for (int ni = 0; ni < 4; ++ni)
                    acc[mi][ni] = __builtin_amdgcn_mfma_f32_16x16x32_bf16(
                        a[mi], b[ni], acc[mi][ni], 0, 0, 0);
        }
        __syncthreads();
    }

    const int col0 = colBase + wn * 64 + (lane & 15);
    const int rq   = (lane >> 4) * 4;
#pragma unroll
    for (int ni = 0; ni < 4; ++ni) {
        int gc = col0 + ni * 16;
        float bias = bEnc[gc];
#pragma unroll
        for (int mi = 0; mi < 4; ++mi) {
            int gr0 = rowBase + wm * 64 + mi * 16 + rq;
#pragma unroll
            for (int rg = 0; rg < 4; ++rg) {
                float v = acc[mi][ni][rg] + bias;
                zhat[(size_t)(gr0 + rg) * D_DICT + gc] = bfmap(f2bf(v));
            }
        }
    }
}

// ---------------- merged: select top-32 + zero/scatter z + fused decode ----------------
// One row per block. Zero-stores for the z row are issued FIRST (fire-and-forget)
// and drain while the histogram/refine compute runs; the pre-scatter barrier's
// vmcnt(0) guarantees ordering before the scatter stores.
__global__ __launch_bounds__(256) void sel_dec(const unsigned short* __restrict__ zhat,
                                               const float* __restrict__ x,
                                               const float* __restrict__ wEnc,
                                               const float* __restrict__ bEnc,
                                               const float* __restrict__ wDecT,
                                               const float* __restrict__ bDec,
                                               float* __restrict__ zsp,
                                               float* __restrict__ xhat) {
    const int row = blockIdx.x;
    const int tid = threadIdx.x;
    const int waveId = tid >> 6;

    __shared__ int   histc[4][256];    // per-wave histogram copies
    __shared__ float xs[D_IN];
    __shared__ int   cidx[CAND_MAX];
    __shared__ float zc[CAND_MAX];
    __shared__ int   selk[TOPK];
    __shared__ float selv[TOPK];
    __shared__ int   sh_bin, sh_cum, sh_bin2;
    __shared__ int   sh_nstrict, sh_ntie, sh_nsel;

    // load this row's 64 screened values into registers (issued first)
    uint4 r[8];
    const uint4* zr4 = (const uint4*)(zhat + (size_t)row * D_DICT);
#pragma unroll
    for (int i = 0; i < 8; ++i) r[i] = zr4[i * 256 + tid];

    // issue the 64 KB zero-store stream for this z row — overlaps with selection
    {
        float4 z4 = make_float4(0.f, 0.f, 0.f, 0.f);
        float4* zd = (float4*)(zsp + (size_t)row * D_DICT);
#pragma unroll
        for (int i = 0; i < 16; ++i) zd[i * 256 + tid] = z4;
    }

    for (int j = tid; j < D_IN; j += 256) xs[j] = x[(size_t)row * D_IN + j];
    if (tid == 0) { sh_nstrict = 0; sh_ntie = 0; sh_nsel = 0; }

    // -------- two-level radix cut with static floor + fallback --------
    unsigned int floorU = 0xBF80u;  // mapped bf16(1.0); ~4% pass (rank-80 at z~1.5)
    int shift1 = 6;
    const int T = CAND_TARGET;

    for (int att = 0; att < 2; ++att) {
        for (int b = tid; b < 1024; b += 256) ((int*)histc)[b] = 0;
        if (tid == 0) sh_bin = -1;
        __syncthreads();
#pragma unroll
        for (int i = 0; i < 8; ++i) {
            unsigned int w[4] = {r[i].x, r[i].y, r[i].z, r[i].w};
#pragma unroll
            for (int q = 0; q < 4; ++q)
#pragma unroll
                for (int h = 0; h < 2; ++h) {
                    unsigned int u = (w[q] >> (16 * h)) & 0xFFFFu;
                    if (u >= floorU) {
                        int bin = (int)((u - floorU) >> shift1);
                        if (bin > 255) bin = 255;
                        atomicAdd(&histc[waveId][bin], 1);
                    }
                }
        }
        __syncthreads();
        if (tid < 256) histc[0][tid] += histc[1][tid] + histc[2][tid] + histc[3][tid];
        __syncthreads();
        if (tid < 64) {  // wave-0 descending prefix scan over 256 bins
            int l = tid;
            int b0 = 255 - l * 4;
            int s0 = histc[0][b0], s1 = histc[0][b0 - 1],
                s2 = histc[0][b0 - 2], s3 = histc[0][b0 - 3];
            int local = s0 + s1 + s2 + s3;
            int pref = local;
#pragma unroll
            for (int off = 1; off < 64; off <<= 1) {
                int n = __shfl_up(pref, off, 64);
                if (l >= off) pref += n;
            }
            unsigned long long m = __ballot(pref >= T);
            if (m) {
                int first = (int)__ffsll(m) - 1;
                if (l == first) {
                    int cum = pref - local;
                    int b, c;
                    if      (cum + s0 >= T)           { b = b0;     c = cum; }
                    else if (cum + s0 + s1 >= T)      { b = b0 - 1; c = cum + s0; }
                    else if (cum + s0 + s1 + s2 >= T) { b = b0 - 2; c = cum + s0 + s1; }
                    else                              { b = b0 - 3; c = cum + s0 + s1 + s2; }
                    sh_bin = b; sh_cum = c;
                }
            }
        }
        __syncthreads();
        if (sh_bin >= 0) break;
        floorU = 0u; shift1 = 8;   // fallback: full-range histogram (unreachable in practice)
    }
    const int b1 = sh_bin;
    const int cumAbove = sh_cum;
    const int s2 = shift1 - 6;     // 64 sub-bins

    // -------- fine pass within coarse bin b1 --------
    for (int b = tid; b < 1024; b += 256) ((int*)histc)[b] = 0;
    __syncthreads();
#pragma unroll
    for (int i = 0; i < 8; ++i) {
        unsigned int w[4] = {r[i].x, r[i].y, r[i].z, r[i].w};
#pragma unroll
        for (int q = 0; q < 4; ++q)
#pragma unroll
            for (int h = 0; h < 2; ++h) {
                unsigned int u = (w[q] >> (16 * h)) & 0xFFFFu;
                if (u >= floorU) {
                    int bin = (int)((u - floorU) >> shift1);
                    if (bin > 255) bin = 255;
                    if (bin == b1) {
                        int bin2 = (int)(((u - floorU) >> s2) & 63u);
                        atomicAdd(&histc[waveId][bin2], 1);
                    }
                }
            }
    }
    __syncthreads();
    if (tid < 64) {  // wave-0 descending scan over 64 sub-bins
        int l = tid;
        int bb = 63 - l;
        int local = histc[0][bb] + histc[1][bb] + histc[2][bb] + histc[3][bb];
        int pref = local;
#pragma unroll
        for (int off = 1; off < 64; off <<= 1) {
            int n = __shfl_up(pref, off, 64);
            if (l >= off) pref += n;
        }
        unsigned long long m = __ballot(cumAbove + pref >= T);
        int first = (int)__ffsll(m) - 1;
        if (l == first) sh_bin2 = bb;
    }
    __syncthreads();
    const unsigned int tieLo  = floorU + ((unsigned)b1 << shift1) + ((unsigned)sh_bin2 << s2);
    const unsigned int tieTop = tieLo + (1u << s2) - 1u;

    // -------- collect candidates from registers --------
#pragma unroll
    for (int i = 0; i < 8; ++i) {
        unsigned int w[4] = {r[i].x, r[i].y, r[i].z, r[i].w};
#pragma unroll
        for (int q = 0; q < 4; ++q)
#pragma unroll
            for (int h = 0; h < 2; ++h) {
                unsigned int u = (w[q] >> (16 * h)) & 0xFFFFu;
                if (u > tieTop) {
                    int p = atomicAdd(&sh_nstrict, 1);   // < CAND_TARGET guaranteed
                    cidx[p] = (i * 256 + tid) * 8 + q * 2 + h;
                } else if (u >= tieLo) {
                    int t = atomicAdd(&sh_ntie, 1);
                    if (t < CAND_TARGET) cidx[CAND_MAX - 1 - t] = (i * 256 + tid) * 8 + q * 2 + h;
                }
            }
    }
    __syncthreads();
    const int nstrict = sh_nstrict;
    const int nt = min(sh_ntie, CAND_TARGET);
    int tmpv = 0;
    if (tid < nt) tmpv = cidx[CAND_MAX - 1 - tid];
    __syncthreads();
    if (tid < nt) cidx[nstrict + tid] = tmpv;
    __syncthreads();
    const int nc = nstrict + nt;   // in [CAND_TARGET, CAND_MAX)

    // -------- fp64-exact refinement: 4 lanes per candidate --------
    const int sub = tid & 3;
    const int cq  = tid >> 2;
    for (int c0 = 0; c0 < nc; c0 += 64) {
        int c = c0 + cq;
        double acc = 0.0;
        int k = 0;
        if (c < nc) {
            k = cidx[c];
            const float* w  = wEnc + (size_t)k * D_IN + sub * 192;
            const float* xp = xs + sub * 192;
#pragma unroll 8
            for (int j = 0; j < 192; ++j) acc += (double)xp[j] * (double)w[j];
        }
        acc += __shfl_xor(acc, 1, 64);
        acc += __shfl_xor(acc, 2, 64);
        if (c < nc && sub == 0) zc[c] = (float)(acc + (double)bEnc[k]);
    }
    __syncthreads();

    // -------- exact rank (fp32 values, lower-index tie-break) -> top-32 --------
    if (tid < nc) {
        float v = zc[tid];
        int   k = cidx[tid];
        int rk = 0;
        for (int j = 0; j < nc; ++j) {
            float vj = zc[j];
            if (vj > v || (vj == v && cidx[j] < k)) ++rk;
        }
        if (rk < TOPK) {
            int s = atomicAdd(&sh_nsel, 1);
            selk[s] = k; selv[s] = v;
        }
    }
    __syncthreads();   // also drains vmcnt(0): zero-stores complete before scatter

    if (tid < TOPK) zsp[(size_t)row * D_DICT + selk[tid]] = selv[tid];

    // fused decode: x_hat[row] = sum_j selv[j] * W_decT[selk[j], :] + b_dec
    for (int d = tid; d < D_IN; d += 256) {
        float acc = bDec[d];
#pragma unroll
        for (int j = 0; j < TOPK; ++j)
            acc += selv[j] * wDecT[(size_t)selk[j] * D_IN + d];
        xhat[(size_t)row * D_IN + d] = acc;
    }
}

extern "C" void kernel_launch(void* const* d_in, const int* in_sizes, int n_in,
                              void* d_out, int out_size, void* d_ws, size_t ws_size,
                              hipStream_t stream) {
    const float* x    = (const float*)d_in[0];
    const float* wEnc = (const float*)d_in[1];
    const float* bEnc = (const float*)d_in[2];
    const float* wDec = (const float*)d_in[3];
    const float* bDec = (const float*)d_in[4];

    float* xhat = (float*)d_out;                          // [8192][768]
    float* zsp  = (float*)d_out + (size_t)NROWS * D_IN;   // [8192][16384]

    char* ws = (char*)d_ws;
    unsigned short* Xb   = (unsigned short*)ws;                                 // 12.6 MB
    unsigned short* Wb   = (unsigned short*)(ws + (size_t)NROWS * D_IN * 2);    // 25.2 MB
    float*          WdT  = (float*)(ws + (size_t)NROWS * D_IN * 2
                                       + (size_t)D_DICT * D_IN * 2);            // 50.3 MB
    unsigned short* zhat = (unsigned short*)(ws + 88080384);                    // 268 MB (u16[8192][16384])

    {
        int n4 = NROWS * D_IN / 4;
        cast_bf16<<<(n4 + 255) / 256, 256, 0, stream>>>((const float4*)x, (u16x4*)Xb, n4);
    }
    {
        int n4 = D_DICT * D_IN / 4;
        cast_bf16<<<(n4 + 255) / 256, 256, 0, stream>>>((const float4*)wEnc, (u16x4*)Wb, n4);
    }
    transpose_wdec<<<dim3(D_DICT / 32, D_IN / 32), dim3(32, 8), 0, stream>>>(wDec, WdT);
    gemm_enc<<<dim3(D_DICT / 128, NROWS / 128), 256, 0, stream>>>(Xb, Wb, bEnc, zhat);
    sel_dec<<<NROWS, 256, 0, stream>>>(zhat, x, wEnc, bEnc, WdT, bDec, zsp, xhat);
}